// Round 2
// baseline (1483.646 us; speedup 1.0000x reference)
//
#include <hip/hip_runtime.h>
#include <hip/hip_bf16.h>

typedef __hip_bfloat16 bf16;

#define B_   8
#define C_   192
#define OC3  576
#define H_   128
#define W_   128
#define HW_  16384
#define HEADS_ 4
#define D_   48

__device__ __forceinline__ float b2f(bf16 v) { return __bfloat162float(v); }

__device__ __forceinline__ float ldv(const bf16* p)  { return __bfloat162float(*p); }
__device__ __forceinline__ float ldv(const float* p) { return *p; }
__device__ __forceinline__ void  stv(bf16* p, float v)  { *p = __float2bfloat16(v); }
__device__ __forceinline__ void  stv(float* p, float v) { *p = v; }

// ---------------------------------------------------------------------------
// 1x1 conv as GEMM: Y[b,o,p] = sum_c W[o,c] * X[b,c,p] + bias[o]
// grid: (NP/64, O/64, B), block 256 (16x16), 64x64 tile, K chunks of 16.
// Weights/bias are fp32 (as delivered); X/Y dtype templated.
// ---------------------------------------------------------------------------
template<typename TIn, typename TOut>
__global__ void gemm1x1(const float* __restrict__ Wt, const TIn* __restrict__ X,
                        const float* __restrict__ bias, TOut* __restrict__ Y,
                        int O, int K) {
    const int b  = blockIdx.z;
    const int o0 = blockIdx.y * 64;
    const int p0 = blockIdx.x * 64;
    const TIn* Xb = X + (size_t)b * K * HW_;
    TOut*      Yb = Y + (size_t)b * O * HW_;

    __shared__ float Ws[16][65];
    __shared__ float Xs[16][65];

    const int tx = threadIdx.x & 15;
    const int ty = threadIdx.x >> 4;

    float acc[4][4] = {};

    for (int k0 = 0; k0 < K; k0 += 16) {
        // Ws[kk][oo] = W[(o0+oo)*K + k0+kk]   (coalesced over kk)
        for (int t = threadIdx.x; t < 16 * 64; t += 256) {
            int kk = t & 15, oo = t >> 4;
            Ws[kk][oo] = Wt[(size_t)(o0 + oo) * K + k0 + kk];
        }
        // Xs[kk][pp] = X[(k0+kk)*HW + p0+pp]  (coalesced over pp)
        for (int t = threadIdx.x; t < 16 * 64; t += 256) {
            int pp = t & 63, kk = t >> 6;
            Xs[kk][pp] = ldv(&Xb[(size_t)(k0 + kk) * HW_ + p0 + pp]);
        }
        __syncthreads();
#pragma unroll
        for (int kk = 0; kk < 16; ++kk) {
            float a[4], bb[4];
#pragma unroll
            for (int i = 0; i < 4; ++i) a[i]  = Ws[kk][ty + 16 * i];
#pragma unroll
            for (int j = 0; j < 4; ++j) bb[j] = Xs[kk][tx + 16 * j];
#pragma unroll
            for (int i = 0; i < 4; ++i)
#pragma unroll
                for (int j = 0; j < 4; ++j) acc[i][j] += a[i] * bb[j];
        }
        __syncthreads();
    }

#pragma unroll
    for (int i = 0; i < 4; ++i) {
        int o = o0 + ty + 16 * i;
        float bi = bias[o];
#pragma unroll
        for (int j = 0; j < 4; ++j) {
            int p = p0 + tx + 16 * j;
            stv(&Yb[(size_t)o * HW_ + p], acc[i][j] + bi);
        }
    }
}

// ---------------------------------------------------------------------------
// depthwise 3x3, pad 1. grid: (HW/256, 576, B), block 256.
// ---------------------------------------------------------------------------
__global__ void dwconv3x3(const bf16* __restrict__ in, const float* __restrict__ w9,
                          const float* __restrict__ bias, bf16* __restrict__ out) {
    const int p  = blockIdx.x * 256 + threadIdx.x;
    const int ch = blockIdx.y;
    const int b  = blockIdx.z;
    const int y = p >> 7, x = p & 127;
    const bf16* ib = in + ((size_t)b * OC3 + ch) * HW_;

    float wv[9];
#pragma unroll
    for (int i = 0; i < 9; ++i) wv[i] = w9[ch * 9 + i];

    float s = bias[ch];
#pragma unroll
    for (int dy = -1; dy <= 1; ++dy) {
        int yy = y + dy;
        if (yy < 0 || yy > 127) continue;
#pragma unroll
        for (int dx = -1; dx <= 1; ++dx) {
            int xx = x + dx;
            if (xx < 0 || xx > 127) continue;
            s += wv[(dy + 1) * 3 + (dx + 1)] * b2f(ib[yy * 128 + xx]);
        }
    }
    out[((size_t)b * OC3 + ch) * HW_ + p] = __float2bfloat16(s);
}

// ---------------------------------------------------------------------------
// reciprocal L2 norms for q,k rows (channels 0..383). grid: (384, B), block 256
// ---------------------------------------------------------------------------
__global__ void rownorm(const bf16* __restrict__ qkv2, float* __restrict__ rnorm) {
    const int ch = blockIdx.x, b = blockIdx.y;
    const bf16* row = qkv2 + ((size_t)b * OC3 + ch) * HW_;
    float s = 0.f;
    for (int i = threadIdx.x; i < HW_; i += 256) {
        float v = b2f(row[i]);
        s += v * v;
    }
    __shared__ float red[256];
    red[threadIdx.x] = s;
    __syncthreads();
    for (int st = 128; st > 0; st >>= 1) {
        if (threadIdx.x < st) red[threadIdx.x] += red[threadIdx.x + st];
        __syncthreads();
    }
    if (threadIdx.x == 0)
        rnorm[b * 384 + ch] = 1.0f / fmaxf(sqrtf(red[0]), 1e-12f);
}

// ---------------------------------------------------------------------------
// partial S[i][j] = sum_{n in slice} q[i,n]*k[j,n]  (unnormalized rows)
// grid: (8 slices, HEADS, B), block 256 (16x16), each thread 3x3 pairs.
// slice covers 2048 n, staged in 16 sub-chunks of 128 through LDS (fp32).
// ---------------------------------------------------------------------------
__global__ void qk_partial(const bf16* __restrict__ qkv2, float* __restrict__ Spart) {
    const int slice = blockIdx.x, h = blockIdx.y, b = blockIdx.z;
    const bf16* qb = qkv2 + ((size_t)b * OC3 + h * D_) * HW_;
    const bf16* kb = qkv2 + ((size_t)b * OC3 + 192 + h * D_) * HW_;

    __shared__ float qs[48][130];
    __shared__ float ks[48][130];

    const int tx = threadIdx.x & 15;
    const int ty = threadIdx.x >> 4;

    float acc[3][3] = {};

    for (int sub = 0; sub < 16; ++sub) {
        const int n0 = slice * 2048 + sub * 128;
        __syncthreads();
        for (int t = threadIdx.x; t < 48 * 128; t += 256) {
            int r = t >> 7, c = t & 127;
            qs[r][c] = b2f(qb[(size_t)r * HW_ + n0 + c]);
            ks[r][c] = b2f(kb[(size_t)r * HW_ + n0 + c]);
        }
        __syncthreads();
        for (int c = 0; c < 128; ++c) {
            float qv[3], kv[3];
#pragma unroll
            for (int a = 0; a < 3; ++a) qv[a] = qs[ty + 16 * a][c];
#pragma unroll
            for (int e = 0; e < 3; ++e) kv[e] = ks[tx + 16 * e][c];
#pragma unroll
            for (int a = 0; a < 3; ++a)
#pragma unroll
                for (int e = 0; e < 3; ++e) acc[a][e] += qv[a] * kv[e];
        }
    }

    float* outp = Spart + ((size_t)((b * HEADS_ + h) * 8 + slice)) * 2304;
#pragma unroll
    for (int a = 0; a < 3; ++a)
#pragma unroll
        for (int e = 0; e < 3; ++e)
            outp[(ty + 16 * a) * 48 + (tx + 16 * e)] = acc[a][e];
}

// ---------------------------------------------------------------------------
// reduce slices, apply norms+temperature, softmax over j. grid: (HEADS, B), 64thr
// ---------------------------------------------------------------------------
__global__ void softmax48(const float* __restrict__ Spart, const float* __restrict__ rnorm,
                          const float* __restrict__ temp, float* __restrict__ A) {
    const int h = blockIdx.x, b = blockIdx.y;
    const int i = threadIdx.x;
    if (i >= 48) return;
    const float* rq = rnorm + b * 384 + h * D_;
    const float* rk = rnorm + b * 384 + 192 + h * D_;
    const float t = temp[h];
    const float* Sp = Spart + ((size_t)(b * HEADS_ + h) * 8) * 2304;

    float s[48];
#pragma unroll
    for (int j = 0; j < 48; ++j) {
        float v = 0.f;
        for (int sl = 0; sl < 8; ++sl) v += Sp[sl * 2304 + i * 48 + j];
        s[j] = v * rq[i] * rk[j] * t;
    }
    float m = -1e30f;
#pragma unroll
    for (int j = 0; j < 48; ++j) m = fmaxf(m, s[j]);
    float sum = 0.f;
#pragma unroll
    for (int j = 0; j < 48; ++j) { s[j] = expf(s[j] - m); sum += s[j]; }
    float inv = 1.0f / sum;
    float* Ao = A + ((size_t)(b * HEADS_ + h) * 48 + i) * 48;
#pragma unroll
    for (int j = 0; j < 48; ++j) Ao[j] = s[j] * inv;
}

// ---------------------------------------------------------------------------
// out[b, h*48+i, p] = sum_j A[i][j] * v[j,p].  grid: (HW/256, HEADS, B), 256thr
// ---------------------------------------------------------------------------
__global__ void av(const float* __restrict__ A, const bf16* __restrict__ qkv2,
                   float* __restrict__ outc) {
    const int p = blockIdx.x * 256 + threadIdx.x;
    const int h = blockIdx.y, b = blockIdx.z;
    const bf16* vb = qkv2 + ((size_t)b * OC3 + 384 + h * D_) * HW_;

    __shared__ float As[48][48];
    for (int t = threadIdx.x; t < 2304; t += 256)
        As[t / 48][t % 48] = A[(size_t)(b * HEADS_ + h) * 2304 + t];
    __syncthreads();

    float o[48] = {};
    for (int j = 0; j < 48; ++j) {
        float vj = b2f(vb[(size_t)j * HW_ + p]);
#pragma unroll
        for (int i = 0; i < 48; ++i) o[i] += As[i][j] * vj;
    }
    float* ob = outc + ((size_t)b * C_ + h * D_) * HW_;
#pragma unroll
    for (int i = 0; i < 48; ++i) ob[(size_t)i * HW_ + p] = o[i];
}

// ---------------------------------------------------------------------------
extern "C" void kernel_launch(void* const* d_in, const int* in_sizes, int n_in,
                              void* d_out, int out_size, void* d_ws, size_t ws_size,
                              hipStream_t stream) {
    // Reference dtypes are float32 for every input and the output.
    const float* x      = (const float*)d_in[0];
    const float* qkv_w  = (const float*)d_in[1];
    const float* qkv_b  = (const float*)d_in[2];
    const float* dw_w   = (const float*)d_in[3];
    const float* dw_b   = (const float*)d_in[4];
    const float* temp   = (const float*)d_in[5];
    const float* proj_w = (const float*)d_in[6];
    const float* proj_b = (const float*)d_in[7];
    float* out = (float*)d_out;

    char* ws = (char*)d_ws;
    const size_t QKV_BYTES = (size_t)B_ * OC3 * HW_ * sizeof(bf16);  // 150,994,944
    bf16*  bufA  = (bf16*)ws;                                  // qkv after 1x1 (bf16 staging)
    bf16*  bufB  = (bf16*)(ws + QKV_BYTES);                    // qkv after dwconv
    float* rnorm = (float*)(ws + 2 * QKV_BYTES);               // 12,288 B
    float* Spart = (float*)(ws + 2 * QKV_BYTES + 12288);       // 2,359,296 B
    float* Attn  = (float*)(ws + 2 * QKV_BYTES + 12288 + 2359296);  // 294,912 B
    float* bufC  = (float*)ws;  // attention out fp32, aliases bufA (dead by then)

    gemm1x1<float, bf16><<<dim3(HW_ / 64, OC3 / 64, B_), 256, 0, stream>>>(
        qkv_w, x, qkv_b, bufA, OC3, C_);

    dwconv3x3<<<dim3(HW_ / 256, OC3, B_), 256, 0, stream>>>(bufA, dw_w, dw_b, bufB);

    rownorm<<<dim3(384, B_), 256, 0, stream>>>(bufB, rnorm);

    qk_partial<<<dim3(8, HEADS_, B_), 256, 0, stream>>>(bufB, Spart);

    softmax48<<<dim3(HEADS_, B_), 64, 0, stream>>>(Spart, rnorm, temp, Attn);

    av<<<dim3(HW_ / 256, HEADS_, B_), 256, 0, stream>>>(Attn, bufB, bufC);

    gemm1x1<float, float><<<dim3(HW_ / 64, C_ / 64, B_), 256, 0, stream>>>(
        proj_w, bufC, proj_b, out, C_, C_);
}

// Round 3
// 1026.255 us; speedup vs baseline: 1.4457x; 1.4457x over previous
//
#include <hip/hip_runtime.h>
#include <hip/hip_bf16.h>

typedef __hip_bfloat16 bf16;

#define B_   8
#define C_   192
#define OC3  576
#define H_   128
#define W_   128
#define HW_  16384
#define HEADS_ 4
#define D_   48

typedef float f32x4 __attribute__((ext_vector_type(4)));
typedef __bf16 bf16x8 __attribute__((ext_vector_type(8)));

__device__ __forceinline__ float b2f(bf16 v) { return __bfloat162float(v); }
__device__ __forceinline__ void  stv(bf16* p, float v)  { *p = __float2bfloat16(v); }
__device__ __forceinline__ void  stv(float* p, float v) { *p = v; }

// async 16B global -> LDS (dest = wave-uniform base + lane*16)
__device__ __forceinline__ void llds16(const void* g, void* l) {
    __builtin_amdgcn_global_load_lds(
        (const __attribute__((address_space(1))) unsigned int*)g,
        (__attribute__((address_space(3))) unsigned int*)l, 16, 0, 0);
}

// ---------------------------------------------------------------------------
// Convert qkv_w (576x192) and proj_w (192x192) fp32 -> bf16 padded-row buffers.
// grid 768 blocks x 192 threads. Padding rows left as (finite) poison.
// ---------------------------------------------------------------------------
__global__ void cvt_w(const float* __restrict__ qkv_w, const float* __restrict__ proj_w,
                      __bf16* __restrict__ Wq, __bf16* __restrict__ Wp) {
    const int row = blockIdx.x, c = threadIdx.x;
    if (row < OC3) Wq[row * C_ + c] = (__bf16)qkv_w[row * C_ + c];
    else           Wp[(row - OC3) * C_ + c] = (__bf16)proj_w[(row - OC3) * C_ + c];
}

// ---------------------------------------------------------------------------
// Transpose-convert x[b][c][p] fp32 -> Xt[b][p][c] bf16.
// grid (HW/128, 1, B), 256 threads. LDS tile 128p x 192c (padded to 196).
// ---------------------------------------------------------------------------
__global__ void tx_cvt(const float* __restrict__ x, __bf16* __restrict__ Xt) {
    const int p0 = blockIdx.x * 128;
    const int b  = blockIdx.z;
    __shared__ __bf16 LT[128 * 196];

    for (int idx = threadIdx.x; idx < C_ * 128; idx += 256) {
        int c = idx >> 7, pp = idx & 127;
        LT[pp * 196 + c] = (__bf16)x[((size_t)b * C_ + c) * HW_ + p0 + pp];
    }
    __syncthreads();
    for (int idx = threadIdx.x; idx < 128 * 48; idx += 256) {
        int pp = idx / 48, c4 = idx % 48;
        *(uint2*)&Xt[((size_t)b * HW_ + p0 + pp) * C_ + c4 * 4] =
            *(const uint2*)&LT[pp * 196 + c4 * 4];
    }
}

// ---------------------------------------------------------------------------
// MFMA GEMM (BT form): Y[b][o][p] = sum_k Wp[o][k] * Xt[b][p][k] + bias[o]
// Wp rows padded to grid_y*128 (garbage rows masked at store).
// grid (HW/128, ceil(O/128), B), 256 threads (4 waves, each 64x64).
// ---------------------------------------------------------------------------
template<typename TOut>
__global__ __launch_bounds__(256) void mfma_gemm(
        const __bf16* __restrict__ Wp, const __bf16* __restrict__ Xt,
        const float* __restrict__ bias, TOut* __restrict__ Y,
        const int O, const int K) {
    const int tid  = threadIdx.x;
    const int wid  = tid >> 6, lane = tid & 63;
    const int lm   = lane & 15, qd = lane >> 4;
    const int p0   = blockIdx.x * 128;
    const int o0   = blockIdx.y * 128;
    const int b    = blockIdx.z;
    const int wo0  = (wid >> 1) * 64, wn0 = (wid & 1) * 64;

    const __bf16* Wb = Wp + (size_t)o0 * K;
    const __bf16* Xb = Xt + ((size_t)b * HW_ + p0) * K;

    __shared__ __bf16 As[128 * 32];
    __shared__ __bf16 Bs[128 * 32];

    f32x4 acc[4][4] = {};

    for (int k0 = 0; k0 < K; k0 += 32) {
#pragma unroll
        for (int r = 0; r < 2; ++r) {
            int slot = r * 256 + tid;
            int row = slot >> 2, k8 = slot & 3;
            const __bf16* gA = Wb + (size_t)row * K + k0 + k8 * 8;
            const __bf16* gB = Xb + (size_t)row * K + k0 + k8 * 8;
            __bf16* lA = As + (size_t)(r * 256 + wid * 64) * 8;
            __bf16* lB = Bs + (size_t)(r * 256 + wid * 64) * 8;
            llds16(gA, lA);
            llds16(gB, lB);
        }
        __syncthreads();

        bf16x8 af[4], bfr[4];
#pragma unroll
        for (int i = 0; i < 4; ++i)
            af[i] = *(const bf16x8*)&As[(wo0 + i * 16 + lm) * 32 + qd * 8];
#pragma unroll
        for (int j = 0; j < 4; ++j)
            bfr[j] = *(const bf16x8*)&Bs[(wn0 + j * 16 + lm) * 32 + qd * 8];
#pragma unroll
        for (int i = 0; i < 4; ++i)
#pragma unroll
            for (int j = 0; j < 4; ++j)
                acc[i][j] = __builtin_amdgcn_mfma_f32_16x16x32_bf16(
                    af[i], bfr[j], acc[i][j], 0, 0, 0);
        __syncthreads();
    }

    TOut* Yb = Y + (size_t)b * O * HW_;
#pragma unroll
    for (int i = 0; i < 4; ++i) {
#pragma unroll
        for (int j = 0; j < 4; ++j) {
            const int p = p0 + wn0 + j * 16 + lm;
#pragma unroll
            for (int r = 0; r < 4; ++r) {
                const int o = o0 + wo0 + i * 16 + qd * 4 + r;
                if (o < O)
                    stv(&Yb[(size_t)o * HW_ + p], acc[i][j][r] + bias[o]);
            }
        }
    }
}

// ---------------------------------------------------------------------------
// depthwise 3x3, pad 1. grid: (HW/256, 576, B), block 256.
// ---------------------------------------------------------------------------
__global__ void dwconv3x3(const bf16* __restrict__ in, const float* __restrict__ w9,
                          const float* __restrict__ bias, bf16* __restrict__ out) {
    const int p  = blockIdx.x * 256 + threadIdx.x;
    const int ch = blockIdx.y;
    const int b  = blockIdx.z;
    const int y = p >> 7, x = p & 127;
    const bf16* ib = in + ((size_t)b * OC3 + ch) * HW_;

    float wv[9];
#pragma unroll
    for (int i = 0; i < 9; ++i) wv[i] = w9[ch * 9 + i];

    float s = bias[ch];
#pragma unroll
    for (int dy = -1; dy <= 1; ++dy) {
        int yy = y + dy;
        if (yy < 0 || yy > 127) continue;
#pragma unroll
        for (int dx = -1; dx <= 1; ++dx) {
            int xx = x + dx;
            if (xx < 0 || xx > 127) continue;
            s += wv[(dy + 1) * 3 + (dx + 1)] * b2f(ib[yy * 128 + xx]);
        }
    }
    out[((size_t)b * OC3 + ch) * HW_ + p] = __float2bfloat16(s);
}

// ---------------------------------------------------------------------------
// reciprocal L2 norms for q,k rows (channels 0..383). grid: (384, B), block 256
// ---------------------------------------------------------------------------
__global__ void rownorm(const bf16* __restrict__ qkv2, float* __restrict__ rnorm) {
    const int ch = blockIdx.x, b = blockIdx.y;
    const bf16* row = qkv2 + ((size_t)b * OC3 + ch) * HW_;
    float s = 0.f;
    for (int i = threadIdx.x; i < HW_; i += 256) {
        float v = b2f(row[i]);
        s += v * v;
    }
    __shared__ float red[256];
    red[threadIdx.x] = s;
    __syncthreads();
    for (int st = 128; st > 0; st >>= 1) {
        if (threadIdx.x < st) red[threadIdx.x] += red[threadIdx.x + st];
        __syncthreads();
    }
    if (threadIdx.x == 0)
        rnorm[b * 384 + ch] = 1.0f / fmaxf(sqrtf(red[0]), 1e-12f);
}

// ---------------------------------------------------------------------------
// partial S[i][j] = sum_{n in slice} q[i,n]*k[j,n]  (unnormalized rows)
// ---------------------------------------------------------------------------
__global__ void qk_partial(const bf16* __restrict__ qkv2, float* __restrict__ Spart) {
    const int slice = blockIdx.x, h = blockIdx.y, b = blockIdx.z;
    const bf16* qb = qkv2 + ((size_t)b * OC3 + h * D_) * HW_;
    const bf16* kb = qkv2 + ((size_t)b * OC3 + 192 + h * D_) * HW_;

    __shared__ float qs[48][130];
    __shared__ float ks[48][130];

    const int tx = threadIdx.x & 15;
    const int ty = threadIdx.x >> 4;

    float acc[3][3] = {};

    for (int sub = 0; sub < 16; ++sub) {
        const int n0 = slice * 2048 + sub * 128;
        __syncthreads();
        for (int t = threadIdx.x; t < 48 * 128; t += 256) {
            int r = t >> 7, c = t & 127;
            qs[r][c] = b2f(qb[(size_t)r * HW_ + n0 + c]);
            ks[r][c] = b2f(kb[(size_t)r * HW_ + n0 + c]);
        }
        __syncthreads();
        for (int c = 0; c < 128; ++c) {
            float qv[3], kv[3];
#pragma unroll
            for (int a = 0; a < 3; ++a) qv[a] = qs[ty + 16 * a][c];
#pragma unroll
            for (int e = 0; e < 3; ++e) kv[e] = ks[tx + 16 * e][c];
#pragma unroll
            for (int a = 0; a < 3; ++a)
#pragma unroll
                for (int e = 0; e < 3; ++e) acc[a][e] += qv[a] * kv[e];
        }
    }

    float* outp = Spart + ((size_t)((b * HEADS_ + h) * 8 + slice)) * 2304;
#pragma unroll
    for (int a = 0; a < 3; ++a)
#pragma unroll
        for (int e = 0; e < 3; ++e)
            outp[(ty + 16 * a) * 48 + (tx + 16 * e)] = acc[a][e];
}

// ---------------------------------------------------------------------------
// reduce slices, apply norms+temperature, softmax over j. grid: (HEADS, B), 64thr
// ---------------------------------------------------------------------------
__global__ void softmax48(const float* __restrict__ Spart, const float* __restrict__ rnorm,
                          const float* __restrict__ temp, float* __restrict__ A) {
    const int h = blockIdx.x, b = blockIdx.y;
    const int i = threadIdx.x;
    if (i >= 48) return;
    const float* rq = rnorm + b * 384 + h * D_;
    const float* rk = rnorm + b * 384 + 192 + h * D_;
    const float t = temp[h];
    const float* Sp = Spart + ((size_t)(b * HEADS_ + h) * 8) * 2304;

    float s[48];
#pragma unroll
    for (int j = 0; j < 48; ++j) {
        float v = 0.f;
        for (int sl = 0; sl < 8; ++sl) v += Sp[sl * 2304 + i * 48 + j];
        s[j] = v * rq[i] * rk[j] * t;
    }
    float m = -1e30f;
#pragma unroll
    for (int j = 0; j < 48; ++j) m = fmaxf(m, s[j]);
    float sum = 0.f;
#pragma unroll
    for (int j = 0; j < 48; ++j) { s[j] = expf(s[j] - m); sum += s[j]; }
    float inv = 1.0f / sum;
    float* Ao = A + ((size_t)(b * HEADS_ + h) * 48 + i) * 48;
#pragma unroll
    for (int j = 0; j < 48; ++j) Ao[j] = s[j] * inv;
}

// ---------------------------------------------------------------------------
// avt[b][p][h*48+i] = sum_j A[i][j] * v[j,p]  (bf16, BT layout for proj GEMM)
// grid: (HW/256, HEADS, B), 256thr
// ---------------------------------------------------------------------------
__global__ void av(const float* __restrict__ A, const bf16* __restrict__ qkv2,
                   __bf16* __restrict__ avt) {
    const int p = blockIdx.x * 256 + threadIdx.x;
    const int h = blockIdx.y, b = blockIdx.z;
    const bf16* vb = qkv2 + ((size_t)b * OC3 + 384 + h * D_) * HW_;

    __shared__ float As[48][48];
    for (int t = threadIdx.x; t < 2304; t += 256)
        As[t / 48][t % 48] = A[(size_t)(b * HEADS_ + h) * 2304 + t];
    __syncthreads();

    float o[48] = {};
    for (int j = 0; j < 48; ++j) {
        float vj = b2f(vb[(size_t)j * HW_ + p]);
#pragma unroll
        for (int i = 0; i < 48; ++i) o[i] += As[i][j] * vj;
    }
    __bf16* ob = avt + ((size_t)b * HW_ + p) * C_ + h * D_;
#pragma unroll
    for (int i = 0; i < 48; ++i) ob[i] = (__bf16)o[i];
}

// ---------------------------------------------------------------------------
extern "C" void kernel_launch(void* const* d_in, const int* in_sizes, int n_in,
                              void* d_out, int out_size, void* d_ws, size_t ws_size,
                              hipStream_t stream) {
    const float* x      = (const float*)d_in[0];
    const float* qkv_w  = (const float*)d_in[1];
    const float* qkv_b  = (const float*)d_in[2];
    const float* dw_w   = (const float*)d_in[3];
    const float* dw_b   = (const float*)d_in[4];
    const float* temp   = (const float*)d_in[5];
    const float* proj_w = (const float*)d_in[6];
    const float* proj_b = (const float*)d_in[7];
    float* out = (float*)d_out;

    char* ws = (char*)d_ws;
    const size_t XT_BYTES  = (size_t)B_ * HW_ * C_ * 2;      // 50,331,648
    const size_t WQ_BYTES  = 640 * C_ * 2;                   // 245,760 (padded)
    const size_t WP_BYTES  = 256 * C_ * 2;                   // 98,304  (padded)
    const size_t QKV_BYTES = (size_t)B_ * OC3 * HW_ * 2;     // 150,994,944

    size_t off = 0;
    __bf16* Xt    = (__bf16*)(ws + off); off += XT_BYTES;    // aliased by avt later
    __bf16* Wq    = (__bf16*)(ws + off); off += WQ_BYTES;
    __bf16* Wp    = (__bf16*)(ws + off); off += WP_BYTES;
    bf16*   bufA  = (bf16*)(ws + off);   off += QKV_BYTES;   // qkv after 1x1
    bf16*   bufB  = (bf16*)(ws + off);   off += QKV_BYTES;   // qkv after dwconv
    float*  rnormp= (float*)(ws + off);  off += 12288;
    float*  Spart = (float*)(ws + off);  off += 2359296;
    float*  Attn  = (float*)(ws + off);  off += 294912;
    __bf16* avt   = Xt;  // Xt dead after qkv GEMM

    cvt_w<<<dim3(768), 192, 0, stream>>>(qkv_w, proj_w, Wq, Wp);

    tx_cvt<<<dim3(HW_ / 128, 1, B_), 256, 0, stream>>>(x, Xt);

    mfma_gemm<bf16><<<dim3(HW_ / 128, 5, B_), 256, 0, stream>>>(
        Wq, Xt, qkv_b, bufA, OC3, C_);

    dwconv3x3<<<dim3(HW_ / 256, OC3, B_), 256, 0, stream>>>(bufA, dw_w, dw_b, bufB);

    rownorm<<<dim3(384, B_), 256, 0, stream>>>(bufB, rnormp);

    qk_partial<<<dim3(8, HEADS_, B_), 256, 0, stream>>>(bufB, Spart);

    softmax48<<<dim3(HEADS_, B_), 64, 0, stream>>>(Spart, rnormp, temp, Attn);

    av<<<dim3(HW_ / 256, HEADS_, B_), 256, 0, stream>>>(Attn, bufB, avt);

    mfma_gemm<float><<<dim3(HW_ / 128, 2, B_), 256, 0, stream>>>(
        Wp, avt, proj_b, out, C_, C_);
}

// Round 4
// 577.218 us; speedup vs baseline: 2.5703x; 1.7779x over previous
//
#include <hip/hip_runtime.h>
#include <hip/hip_bf16.h>

typedef __hip_bfloat16 bf16;

#define B_   8
#define C_   192
#define OC3  576
#define H_   128
#define W_   128
#define HW_  16384
#define HEADS_ 4
#define D_   48

typedef float f32x4 __attribute__((ext_vector_type(4)));
typedef __bf16 bf16x8 __attribute__((ext_vector_type(8)));

__device__ __forceinline__ float b2f(bf16 v) { return __bfloat162float(v); }
__device__ __forceinline__ void  stv(bf16* p, float v)  { *p = __float2bfloat16(v); }
__device__ __forceinline__ void  stv(float* p, float v) { *p = v; }

// async 16B global -> LDS (per-lane global addr; LDS dest = wave-uniform base + lane*16)
__device__ __forceinline__ void llds16(const void* g, void* l) {
    __builtin_amdgcn_global_load_lds(
        (const __attribute__((address_space(1))) unsigned int*)g,
        (__attribute__((address_space(3))) unsigned int*)l, 16, 0, 0);
}

// ---------------------------------------------------------------------------
// Convert qkv_w (576x192) fp32 -> bf16 (rows padded to 640; pad rows = finite
// poison, masked at GEMM store). grid 576 x 192 threads.
// ---------------------------------------------------------------------------
__global__ void cvt_w(const float* __restrict__ qkv_w, __bf16* __restrict__ Wq) {
    const int row = blockIdx.x, c = threadIdx.x;
    Wq[row * C_ + c] = (__bf16)qkv_w[row * C_ + c];
}

// ---------------------------------------------------------------------------
// Transpose-convert x[b][c][p] fp32 -> Xt[b][p][c] bf16.
// ---------------------------------------------------------------------------
__global__ void tx_cvt(const float* __restrict__ x, __bf16* __restrict__ Xt) {
    const int p0 = blockIdx.x * 128;
    const int b  = blockIdx.z;
    __shared__ __bf16 LT[128 * 196];

    for (int idx = threadIdx.x; idx < C_ * 128; idx += 256) {
        int c = idx >> 7, pp = idx & 127;
        LT[pp * 196 + c] = (__bf16)x[((size_t)b * C_ + c) * HW_ + p0 + pp];
    }
    __syncthreads();
    for (int idx = threadIdx.x; idx < 128 * 48; idx += 256) {
        int pp = idx / 48, c4 = idx % 48;
        *(uint2*)&Xt[((size_t)b * HW_ + p0 + pp) * C_ + c4 * 4] =
            *(const uint2*)&LT[pp * 196 + c4 * 4];
    }
}

// ---------------------------------------------------------------------------
// Transpose v-part of qkv2: vt[b][p][c] (c=0..191 => channel 384+c) bf16.
// ---------------------------------------------------------------------------
__global__ void vtx(const bf16* __restrict__ qkv2, __bf16* __restrict__ vt) {
    const int p0 = blockIdx.x * 128;
    const int b  = blockIdx.z;
    const bf16* vb = qkv2 + ((size_t)b * OC3 + 384) * HW_;
    __shared__ __bf16 LT[128 * 200];

    for (int idx = threadIdx.x; idx < C_ * 128; idx += 256) {
        int c = idx >> 7, pp = idx & 127;
        LT[pp * 200 + c] = *(const __bf16*)&vb[(size_t)c * HW_ + p0 + pp];
    }
    __syncthreads();
    for (int idx = threadIdx.x; idx < 128 * 48; idx += 256) {
        int pp = idx / 48, c4 = idx % 48;
        *(uint2*)&vt[((size_t)b * HW_ + p0 + pp) * C_ + c4 * 4] =
            *(const uint2*)&LT[pp * 200 + c4 * 4];
    }
}

// ---------------------------------------------------------------------------
// MFMA GEMM (BT form): Y[b][o][p] = sum_k A[o][k] * Xt[b][p][k] + bias[o]
// A rows padded to grid_y*128; a_bstride selects per-batch A (0 = shared).
// ---------------------------------------------------------------------------
template<typename TOut>
__global__ __launch_bounds__(256) void mfma_gemm(
        const __bf16* __restrict__ Wp, const __bf16* __restrict__ Xt,
        const float* __restrict__ bias, TOut* __restrict__ Y,
        const int O, const int K, const size_t a_bstride) {
    const int tid  = threadIdx.x;
    const int wid  = tid >> 6, lane = tid & 63;
    const int lm   = lane & 15, qd = lane >> 4;
    const int p0   = blockIdx.x * 128;
    const int o0   = blockIdx.y * 128;
    const int b    = blockIdx.z;
    const int wo0  = (wid >> 1) * 64, wn0 = (wid & 1) * 64;

    const __bf16* Wb = Wp + a_bstride * b + (size_t)o0 * K;
    const __bf16* Xb = Xt + ((size_t)b * HW_ + p0) * K;

    __shared__ __bf16 As[128 * 32];
    __shared__ __bf16 Bs[128 * 32];

    f32x4 acc[4][4] = {};

    for (int k0 = 0; k0 < K; k0 += 32) {
#pragma unroll
        for (int r = 0; r < 2; ++r) {
            int slot = r * 256 + tid;
            int row = slot >> 2, k8 = slot & 3;
            const __bf16* gA = Wb + (size_t)row * K + k0 + k8 * 8;
            const __bf16* gB = Xb + (size_t)row * K + k0 + k8 * 8;
            __bf16* lA = As + (size_t)(r * 256 + wid * 64) * 8;
            __bf16* lB = Bs + (size_t)(r * 256 + wid * 64) * 8;
            llds16(gA, lA);
            llds16(gB, lB);
        }
        __syncthreads();

        bf16x8 af[4], bfr[4];
#pragma unroll
        for (int i = 0; i < 4; ++i)
            af[i] = *(const bf16x8*)&As[(wo0 + i * 16 + lm) * 32 + qd * 8];
#pragma unroll
        for (int j = 0; j < 4; ++j)
            bfr[j] = *(const bf16x8*)&Bs[(wn0 + j * 16 + lm) * 32 + qd * 8];
#pragma unroll
        for (int i = 0; i < 4; ++i)
#pragma unroll
            for (int j = 0; j < 4; ++j)
                acc[i][j] = __builtin_amdgcn_mfma_f32_16x16x32_bf16(
                    af[i], bfr[j], acc[i][j], 0, 0, 0);
        __syncthreads();
    }

    TOut* Yb = Y + (size_t)b * O * HW_;
#pragma unroll
    for (int i = 0; i < 4; ++i) {
#pragma unroll
        for (int j = 0; j < 4; ++j) {
            const int p = p0 + wn0 + j * 16 + lm;
#pragma unroll
            for (int r = 0; r < 4; ++r) {
                const int o = o0 + wo0 + i * 16 + qd * 4 + r;
                if (o < O)
                    stv(&Yb[(size_t)o * HW_ + p], acc[i][j][r] + bias[o]);
            }
        }
    }
}

// ---------------------------------------------------------------------------
// depthwise 3x3 + fused sum-of-squares (for q,k L2 norms).
// grid (ch=576, b=8), block 256. Whole 128x128 plane staged in LDS (32 KB).
// Thread t computes the 8x8 tile at (y0=(t>>4)*8, x0=(t&15)*8).
// ---------------------------------------------------------------------------
__device__ __forceinline__ void dw_load_row(const __bf16* plane, int yy, int x0,
                                            float* r) {
    if (yy < 0 || yy > 127) {
#pragma unroll
        for (int i = 0; i < 10; ++i) r[i] = 0.f;
        return;
    }
    const __bf16* row = plane + yy * 128;
    bf16x8 v = *(const bf16x8*)(row + x0);
    r[0] = (x0 > 0) ? (float)row[x0 - 1] : 0.f;
#pragma unroll
    for (int i = 0; i < 8; ++i) r[1 + i] = (float)v[i];
    r[9] = (x0 + 8 < 128) ? (float)row[x0 + 8] : 0.f;
}

__global__ __launch_bounds__(256) void dwconv_fused(
        const bf16* __restrict__ in, const float* __restrict__ w9,
        const float* __restrict__ bias, bf16* __restrict__ out,
        float* __restrict__ sumsq) {
    const int ch = blockIdx.x;
    const int b  = blockIdx.y;
    const int tid = threadIdx.x;
    const char* ib = (const char*)(in + ((size_t)b * OC3 + ch) * HW_);

    __shared__ __bf16 plane[16384];
    __shared__ float red[256];

    // stage 32 KB plane: 4 waves x 8 iters x (64 lanes * 16 B)
    {
        const int wid = tid >> 6, lane = tid & 63;
        char* lbase = (char*)plane + wid * 8192;
        const char* gbase = ib + wid * 8192;
#pragma unroll
        for (int i = 0; i < 8; ++i)
            llds16(gbase + i * 1024 + lane * 16, lbase + i * 1024);
    }

    float wv[9];
#pragma unroll
    for (int i = 0; i < 9; ++i) wv[i] = w9[ch * 9 + i];
    const float bi = bias[ch];

    __syncthreads();

    const int x0 = (tid & 15) * 8;
    const int y0 = (tid >> 4) * 8;
    bf16* ob = out + ((size_t)b * OC3 + ch) * HW_;

    float r0[10], r1[10], r2[10];
    dw_load_row(plane, y0 - 1, x0, r0);
    dw_load_row(plane, y0,     x0, r1);

    float ss = 0.f;
#pragma unroll
    for (int yi = 0; yi < 8; ++yi) {
        dw_load_row(plane, y0 + yi + 1, x0, r2);
        bf16x8 st;
#pragma unroll
        for (int xx = 0; xx < 8; ++xx) {
            float o = bi;
#pragma unroll
            for (int dx = 0; dx < 3; ++dx) {
                o += wv[0 + dx] * r0[xx + dx];
                o += wv[3 + dx] * r1[xx + dx];
                o += wv[6 + dx] * r2[xx + dx];
            }
            ss += o * o;
            st[xx] = (__bf16)o;
        }
        *(bf16x8*)(ob + (y0 + yi) * 128 + x0) = st;
#pragma unroll
        for (int i = 0; i < 10; ++i) { r0[i] = r1[i]; r1[i] = r2[i]; }
    }

    red[tid] = ss;
    __syncthreads();
    for (int stx = 128; stx > 0; stx >>= 1) {
        if (tid < stx) red[tid] += red[tid + stx];
        __syncthreads();
    }
    if (tid == 0) sumsq[b * OC3 + ch] = red[0];
}

// ---------------------------------------------------------------------------
// partial S[i][j] = sum_{n in slice} q[i,n]*k[j,n]  (unnormalized rows)
// grid (8 slices, HEADS, B), block 256 (16x16). Vectorized global staging.
// ---------------------------------------------------------------------------
__global__ void qk_partial(const bf16* __restrict__ qkv2, float* __restrict__ Spart) {
    const int slice = blockIdx.x, h = blockIdx.y, b = blockIdx.z;
    const __bf16* qb = (const __bf16*)(qkv2 + ((size_t)b * OC3 + h * D_) * HW_);
    const __bf16* kb = (const __bf16*)(qkv2 + ((size_t)b * OC3 + 192 + h * D_) * HW_);

    __shared__ float qs[48 * 130];
    __shared__ float ks[48 * 130];

    const int tx = threadIdx.x & 15;
    const int ty = threadIdx.x >> 4;

    float acc[3][3] = {};

    for (int sub = 0; sub < 16; ++sub) {
        const int n0 = slice * 2048 + sub * 128;
        __syncthreads();
#pragma unroll
        for (int i = 0; i < 3; ++i) {
            int v = threadIdx.x + 256 * i;
            int row = v >> 4, c8 = v & 15;
            bf16x8 qv8 = *(const bf16x8*)(qb + (size_t)row * HW_ + n0 + c8 * 8);
            bf16x8 kv8 = *(const bf16x8*)(kb + (size_t)row * HW_ + n0 + c8 * 8);
            float* dq = &qs[row * 130 + c8 * 8];
            float* dk = &ks[row * 130 + c8 * 8];
#pragma unroll
            for (int m = 0; m < 4; ++m) {
                float2 fq = make_float2((float)qv8[2 * m], (float)qv8[2 * m + 1]);
                float2 fk = make_float2((float)kv8[2 * m], (float)kv8[2 * m + 1]);
                *(float2*)(dq + 2 * m) = fq;
                *(float2*)(dk + 2 * m) = fk;
            }
        }
        __syncthreads();
        for (int c = 0; c < 128; ++c) {
            float qv[3], kv[3];
#pragma unroll
            for (int a = 0; a < 3; ++a) qv[a] = qs[(ty + 16 * a) * 130 + c];
#pragma unroll
            for (int e = 0; e < 3; ++e) kv[e] = ks[(tx + 16 * e) * 130 + c];
#pragma unroll
            for (int a = 0; a < 3; ++a)
#pragma unroll
                for (int e = 0; e < 3; ++e) acc[a][e] += qv[a] * kv[e];
        }
    }

    float* outp = Spart + ((size_t)((b * HEADS_ + h) * 8 + slice)) * 2304;
#pragma unroll
    for (int a = 0; a < 3; ++a)
#pragma unroll
        for (int e = 0; e < 3; ++e)
            outp[(ty + 16 * a) * 48 + (tx + 16 * e)] = acc[a][e];
}

// ---------------------------------------------------------------------------
// reduce slices, apply norms (from fused sumsq) + temperature, softmax over j.
// ---------------------------------------------------------------------------
__global__ void softmax48(const float* __restrict__ Spart, const float* __restrict__ sumsq,
                          const float* __restrict__ temp, float* __restrict__ A) {
    const int h = blockIdx.x, b = blockIdx.y;
    const int i = threadIdx.x;
    if (i >= 48) return;
    const float* sq = sumsq + b * OC3 + h * D_;
    const float* sk = sumsq + b * OC3 + 192 + h * D_;
    const float t = temp[h];
    const float* Sp = Spart + ((size_t)(b * HEADS_ + h) * 8) * 2304;

    const float rqi = 1.0f / fmaxf(sqrtf(sq[i]), 1e-12f);

    float s[48];
#pragma unroll
    for (int j = 0; j < 48; ++j) {
        float v = 0.f;
        for (int sl = 0; sl < 8; ++sl) v += Sp[sl * 2304 + i * 48 + j];
        s[j] = v * rqi * (1.0f / fmaxf(sqrtf(sk[j]), 1e-12f)) * t;
    }
    float m = -1e30f;
#pragma unroll
    for (int j = 0; j < 48; ++j) m = fmaxf(m, s[j]);
    float sum = 0.f;
#pragma unroll
    for (int j = 0; j < 48; ++j) { s[j] = expf(s[j] - m); sum += s[j]; }
    float inv = 1.0f / sum;
    float* Ao = A + ((size_t)(b * HEADS_ + h) * 48 + i) * 48;
#pragma unroll
    for (int j = 0; j < 48; ++j) Ao[j] = s[j] * inv;
}

// ---------------------------------------------------------------------------
// Wf[b][o][c'] = sum_i proj_w[o][h*48+i] * A[b,h][i][j]   (c' = h*48+j)
// grid (192 o, 8 b), block 192 (c'). Rows 192..255 of each Wf[b] left poison.
// ---------------------------------------------------------------------------
__global__ void wfuse(const float* __restrict__ proj_w, const float* __restrict__ A,
                      __bf16* __restrict__ Wf) {
    const int o = blockIdx.x, b = blockIdx.y;
    const int cp = threadIdx.x;
    const int h = cp / 48, j = cp % 48;
    const float* wrow = proj_w + o * C_ + h * D_;
    const float* Ah = A + (size_t)(b * HEADS_ + h) * 2304;
    float s = 0.f;
#pragma unroll
    for (int i = 0; i < 48; ++i) s += wrow[i] * Ah[i * 48 + j];
    Wf[((size_t)b * 256 + o) * C_ + cp] = (__bf16)s;
}

// ---------------------------------------------------------------------------
extern "C" void kernel_launch(void* const* d_in, const int* in_sizes, int n_in,
                              void* d_out, int out_size, void* d_ws, size_t ws_size,
                              hipStream_t stream) {
    const float* x      = (const float*)d_in[0];
    const float* qkv_w  = (const float*)d_in[1];
    const float* qkv_b  = (const float*)d_in[2];
    const float* dw_w   = (const float*)d_in[3];
    const float* dw_b   = (const float*)d_in[4];
    const float* temp   = (const float*)d_in[5];
    const float* proj_w = (const float*)d_in[6];
    const float* proj_b = (const float*)d_in[7];
    float* out = (float*)d_out;

    char* ws = (char*)d_ws;
    const size_t XT_BYTES  = (size_t)B_ * HW_ * C_ * 2;      // 50,331,648
    const size_t WQ_BYTES  = 640 * C_ * 2;                   // 245,760 (padded)
    const size_t WF_BYTES  = (size_t)B_ * 256 * C_ * 2;      // 786,432 (padded)
    const size_t QKV_BYTES = (size_t)B_ * OC3 * HW_ * 2;     // 150,994,944

    size_t off = 0;
    __bf16* Xt    = (__bf16*)(ws + off); off += XT_BYTES;    // later reused as vt
    __bf16* Wq    = (__bf16*)(ws + off); off += WQ_BYTES;
    __bf16* Wf    = (__bf16*)(ws + off); off += WF_BYTES;
    bf16*   bufA  = (bf16*)(ws + off);   off += QKV_BYTES;   // qkv after 1x1
    bf16*   bufB  = (bf16*)(ws + off);   off += QKV_BYTES;   // qkv after dwconv
    float*  sumsq = (float*)(ws + off);  off += OC3 * B_ * 4;
    float*  Spart = (float*)(ws + off);  off += 2359296;
    float*  Attn  = (float*)(ws + off);  off += 294912;
    __bf16* vt    = Xt;  // Xt dead after qkv GEMM

    cvt_w<<<dim3(OC3), 192, 0, stream>>>(qkv_w, Wq);

    tx_cvt<<<dim3(HW_ / 128, 1, B_), 256, 0, stream>>>(x, Xt);

    mfma_gemm<bf16><<<dim3(HW_ / 128, 5, B_), 256, 0, stream>>>(
        Wq, Xt, qkv_b, bufA, OC3, C_, 0);

    dwconv_fused<<<dim3(OC3, B_), 256, 0, stream>>>(bufA, dw_w, dw_b, bufB, sumsq);

    qk_partial<<<dim3(8, HEADS_, B_), 256, 0, stream>>>(bufB, Spart);

    softmax48<<<dim3(HEADS_, B_), 64, 0, stream>>>(Spart, sumsq, temp, Attn);

    vtx<<<dim3(HW_ / 128, 1, B_), 256, 0, stream>>>(bufB, vt);

    wfuse<<<dim3(C_, B_), 192, 0, stream>>>(proj_w, Attn, Wf);

    mfma_gemm<float><<<dim3(HW_ / 128, 2, B_), 256, 0, stream>>>(
        Wf, vt, proj_b, out, C_, C_, (size_t)256 * C_);
}

// Round 5
// 501.221 us; speedup vs baseline: 2.9601x; 1.1516x over previous
//
#include <hip/hip_runtime.h>
#include <hip/hip_bf16.h>

typedef __hip_bfloat16 bf16;

#define B_   8
#define C_   192
#define OC3  576
#define H_   128
#define W_   128
#define HW_  16384
#define HEADS_ 4
#define D_   48

typedef float f32x4 __attribute__((ext_vector_type(4)));
typedef __bf16 bf16x8 __attribute__((ext_vector_type(8)));

__device__ __forceinline__ float b2f(bf16 v) { return __bfloat162float(v); }
__device__ __forceinline__ void  stv(bf16* p, float v)  { *p = __float2bfloat16(v); }
__device__ __forceinline__ void  stv(float* p, float v) { *p = v; }

// async 16B global -> LDS (per-lane global addr; LDS dest = wave-uniform base + lane*16)
__device__ __forceinline__ void llds16(const void* g, void* l) {
    __builtin_amdgcn_global_load_lds(
        (const __attribute__((address_space(1))) unsigned int*)g,
        (__attribute__((address_space(3))) unsigned int*)l, 16, 0, 0);
}

// ---------------------------------------------------------------------------
// Convert qkv_w (576x192) fp32 -> bf16 (rows padded to 640; pad rows = finite
// poison, masked at GEMM store). grid 576 x 192 threads.
// ---------------------------------------------------------------------------
__global__ void cvt_w(const float* __restrict__ qkv_w, __bf16* __restrict__ Wq) {
    const int row = blockIdx.x, c = threadIdx.x;
    Wq[row * C_ + c] = (__bf16)qkv_w[row * C_ + c];
}

// ---------------------------------------------------------------------------
// Transpose-convert x[b][c][p] fp32 -> Xt[b][p][c] bf16.
// ---------------------------------------------------------------------------
__global__ void tx_cvt(const float* __restrict__ x, __bf16* __restrict__ Xt) {
    const int p0 = blockIdx.x * 128;
    const int b  = blockIdx.z;
    __shared__ __bf16 LT[128 * 196];

    for (int idx = threadIdx.x; idx < C_ * 128; idx += 256) {
        int c = idx >> 7, pp = idx & 127;
        LT[pp * 196 + c] = (__bf16)x[((size_t)b * C_ + c) * HW_ + p0 + pp];
    }
    __syncthreads();
    for (int idx = threadIdx.x; idx < 128 * 48; idx += 256) {
        int pp = idx / 48, c4 = idx % 48;
        *(uint2*)&Xt[((size_t)b * HW_ + p0 + pp) * C_ + c4 * 4] =
            *(const uint2*)&LT[pp * 196 + c4 * 4];
    }
}

// ---------------------------------------------------------------------------
// Transpose v-part of qkv2: vt[b][p][c] (c=0..191 => channel 384+c) bf16.
// ---------------------------------------------------------------------------
__global__ void vtx(const bf16* __restrict__ qkv2, __bf16* __restrict__ vt) {
    const int p0 = blockIdx.x * 128;
    const int b  = blockIdx.z;
    const bf16* vb = qkv2 + ((size_t)b * OC3 + 384) * HW_;
    __shared__ __bf16 LT[128 * 200];

    for (int idx = threadIdx.x; idx < C_ * 128; idx += 256) {
        int c = idx >> 7, pp = idx & 127;
        LT[pp * 200 + c] = *(const __bf16*)&vb[(size_t)c * HW_ + p0 + pp];
    }
    __syncthreads();
    for (int idx = threadIdx.x; idx < 128 * 48; idx += 256) {
        int pp = idx / 48, c4 = idx % 48;
        *(uint2*)&vt[((size_t)b * HW_ + p0 + pp) * C_ + c4 * 4] =
            *(const uint2*)&LT[pp * 200 + c4 * 4];
    }
}

// ---------------------------------------------------------------------------
// MFMA GEMM (BT form): Y[b][o][p] = sum_k A[o][k] * Xt[b][p][k] + bias[o]
// A rows padded to grid_y*128; a_bstride selects per-batch A (0 = shared).
// ---------------------------------------------------------------------------
template<typename TOut>
__global__ __launch_bounds__(256) void mfma_gemm(
        const __bf16* __restrict__ Wp, const __bf16* __restrict__ Xt,
        const float* __restrict__ bias, TOut* __restrict__ Y,
        const int O, const int K, const size_t a_bstride) {
    const int tid  = threadIdx.x;
    const int wid  = tid >> 6, lane = tid & 63;
    const int lm   = lane & 15, qd = lane >> 4;
    const int p0   = blockIdx.x * 128;
    const int o0   = blockIdx.y * 128;
    const int b    = blockIdx.z;
    const int wo0  = (wid >> 1) * 64, wn0 = (wid & 1) * 64;

    const __bf16* Wb = Wp + a_bstride * b + (size_t)o0 * K;
    const __bf16* Xb = Xt + ((size_t)b * HW_ + p0) * K;

    __shared__ __bf16 As[128 * 32];
    __shared__ __bf16 Bs[128 * 32];

    f32x4 acc[4][4] = {};

    for (int k0 = 0; k0 < K; k0 += 32) {
#pragma unroll
        for (int r = 0; r < 2; ++r) {
            int slot = r * 256 + tid;
            int row = slot >> 2, k8 = slot & 3;
            const __bf16* gA = Wb + (size_t)row * K + k0 + k8 * 8;
            const __bf16* gB = Xb + (size_t)row * K + k0 + k8 * 8;
            __bf16* lA = As + (size_t)(r * 256 + wid * 64) * 8;
            __bf16* lB = Bs + (size_t)(r * 256 + wid * 64) * 8;
            llds16(gA, lA);
            llds16(gB, lB);
        }
        __syncthreads();

        bf16x8 af[4], bfr[4];
#pragma unroll
        for (int i = 0; i < 4; ++i)
            af[i] = *(const bf16x8*)&As[(wo0 + i * 16 + lm) * 32 + qd * 8];
#pragma unroll
        for (int j = 0; j < 4; ++j)
            bfr[j] = *(const bf16x8*)&Bs[(wn0 + j * 16 + lm) * 32 + qd * 8];
#pragma unroll
        for (int i = 0; i < 4; ++i)
#pragma unroll
            for (int j = 0; j < 4; ++j)
                acc[i][j] = __builtin_amdgcn_mfma_f32_16x16x32_bf16(
                    af[i], bfr[j], acc[i][j], 0, 0, 0);
        __syncthreads();
    }

    TOut* Yb = Y + (size_t)b * O * HW_;
#pragma unroll
    for (int i = 0; i < 4; ++i) {
#pragma unroll
        for (int j = 0; j < 4; ++j) {
            const int p = p0 + wn0 + j * 16 + lm;
#pragma unroll
            for (int r = 0; r < 4; ++r) {
                const int o = o0 + wo0 + i * 16 + qd * 4 + r;
                if (o < O)
                    stv(&Yb[(size_t)o * HW_ + p], acc[i][j][r] + bias[o]);
            }
        }
    }
}

// ---------------------------------------------------------------------------
// depthwise 3x3 + fused sum-of-squares (for q,k L2 norms).
// grid (ch=576, b=8), block 256. Whole 128x128 plane staged in LDS (32 KB).
// ---------------------------------------------------------------------------
__device__ __forceinline__ void dw_load_row(const __bf16* plane, int yy, int x0,
                                            float* r) {
    if (yy < 0 || yy > 127) {
#pragma unroll
        for (int i = 0; i < 10; ++i) r[i] = 0.f;
        return;
    }
    const __bf16* row = plane + yy * 128;
    bf16x8 v = *(const bf16x8*)(row + x0);
    r[0] = (x0 > 0) ? (float)row[x0 - 1] : 0.f;
#pragma unroll
    for (int i = 0; i < 8; ++i) r[1 + i] = (float)v[i];
    r[9] = (x0 + 8 < 128) ? (float)row[x0 + 8] : 0.f;
}

__global__ __launch_bounds__(256) void dwconv_fused(
        const bf16* __restrict__ in, const float* __restrict__ w9,
        const float* __restrict__ bias, bf16* __restrict__ out,
        float* __restrict__ sumsq) {
    const int ch = blockIdx.x;
    const int b  = blockIdx.y;
    const int tid = threadIdx.x;
    const char* ib = (const char*)(in + ((size_t)b * OC3 + ch) * HW_);

    __shared__ __bf16 plane[16384];
    __shared__ float red[256];

    {
        const int wid = tid >> 6, lane = tid & 63;
        char* lbase = (char*)plane + wid * 8192;
        const char* gbase = ib + wid * 8192;
#pragma unroll
        for (int i = 0; i < 8; ++i)
            llds16(gbase + i * 1024 + lane * 16, lbase + i * 1024);
    }

    float wv[9];
#pragma unroll
    for (int i = 0; i < 9; ++i) wv[i] = w9[ch * 9 + i];
    const float bi = bias[ch];

    __syncthreads();

    const int x0 = (tid & 15) * 8;
    const int y0 = (tid >> 4) * 8;
    bf16* ob = out + ((size_t)b * OC3 + ch) * HW_;

    float r0[10], r1[10], r2[10];
    dw_load_row(plane, y0 - 1, x0, r0);
    dw_load_row(plane, y0,     x0, r1);

    float ss = 0.f;
#pragma unroll
    for (int yi = 0; yi < 8; ++yi) {
        dw_load_row(plane, y0 + yi + 1, x0, r2);
        bf16x8 st;
#pragma unroll
        for (int xx = 0; xx < 8; ++xx) {
            float o = bi;
#pragma unroll
            for (int dx = 0; dx < 3; ++dx) {
                o += wv[0 + dx] * r0[xx + dx];
                o += wv[3 + dx] * r1[xx + dx];
                o += wv[6 + dx] * r2[xx + dx];
            }
            ss += o * o;
            st[xx] = (__bf16)o;
        }
        *(bf16x8*)(ob + (y0 + yi) * 128 + x0) = st;
#pragma unroll
        for (int i = 0; i < 10; ++i) { r0[i] = r1[i]; r1[i] = r2[i]; }
    }

    red[tid] = ss;
    __syncthreads();
    for (int stx = 128; stx > 0; stx >>= 1) {
        if (tid < stx) red[tid] += red[tid + stx];
        __syncthreads();
    }
    if (tid == 0) sumsq[b * OC3 + ch] = red[0];
}

// ---------------------------------------------------------------------------
// MFMA QK^T partials: S_part[slice][i][j] = sum_{n in 512-slice} q[i,n]*k[j,n]
// grid (32, HEADS, B), 256 thr. LDS: q/k chunks 48x128, rows padded to 136
// (row stride 17*16B => 2-way max bank aliasing on ds_read_b128). 4 waves
// split each 128-chunk into K=32 pieces; fp32 cross-wave reduce in LDS.
// ---------------------------------------------------------------------------
__global__ __launch_bounds__(256) void qk_mfma(const bf16* __restrict__ qkv2,
                                               float* __restrict__ Spart) {
    const int slice = blockIdx.x, h = blockIdx.y, b = blockIdx.z;
    const __bf16* qb = (const __bf16*)(qkv2 + ((size_t)b * OC3 + h * D_) * HW_);
    const __bf16* kb = (const __bf16*)(qkv2 + ((size_t)b * OC3 + 192 + h * D_) * HW_);

    __shared__ char smem[36864];                 // max(staging 26112, reduce 36864)
    __bf16* qs = (__bf16*)smem;                  // 48 x 136
    __bf16* ks = (__bf16*)(smem + 13056);        // 48 x 136
    float*  red = (float*)smem;                  // 4 x 2304

    const int tid = threadIdx.x, wid = tid >> 6, lane = tid & 63;
    const int lm = lane & 15, qd = lane >> 4;
    const int kw0 = wid * 32;

    f32x4 acc[3][3] = {};

    for (int sub = 0; sub < 4; ++sub) {
        const int n0 = slice * 512 + sub * 128;
        __syncthreads();
        for (int t = tid; t < 768; t += 256) {
            int r = t >> 4, c8 = t & 15;
            *(bf16x8*)&qs[r * 136 + c8 * 8] =
                *(const bf16x8*)(qb + (size_t)r * HW_ + n0 + c8 * 8);
            *(bf16x8*)&ks[r * 136 + c8 * 8] =
                *(const bf16x8*)(kb + (size_t)r * HW_ + n0 + c8 * 8);
        }
        __syncthreads();

        bf16x8 af[3], bfr[3];
#pragma unroll
        for (int i = 0; i < 3; ++i)
            af[i] = *(const bf16x8*)&qs[(i * 16 + lm) * 136 + kw0 + qd * 8];
#pragma unroll
        for (int j = 0; j < 3; ++j)
            bfr[j] = *(const bf16x8*)&ks[(j * 16 + lm) * 136 + kw0 + qd * 8];
#pragma unroll
        for (int i = 0; i < 3; ++i)
#pragma unroll
            for (int j = 0; j < 3; ++j)
                acc[i][j] = __builtin_amdgcn_mfma_f32_16x16x32_bf16(
                    af[i], bfr[j], acc[i][j], 0, 0, 0);
    }

    __syncthreads();
    float* wb = red + wid * 2304;
#pragma unroll
    for (int i = 0; i < 3; ++i)
#pragma unroll
        for (int j = 0; j < 3; ++j)
#pragma unroll
            for (int r = 0; r < 4; ++r)
                wb[(i * 16 + qd * 4 + r) * 48 + j * 16 + lm] = acc[i][j][r];
    __syncthreads();

    float* outp = Spart + ((size_t)((b * HEADS_ + h) * 32 + slice)) * 2304;
    for (int t = tid; t < 2304; t += 256)
        outp[t] = red[t] + red[2304 + t] + red[4608 + t] + red[6912 + t];
}

// ---------------------------------------------------------------------------
// reduce 32 slices, apply norms (from fused sumsq) + temperature, softmax.
// ---------------------------------------------------------------------------
__global__ void softmax48(const float* __restrict__ Spart, const float* __restrict__ sumsq,
                          const float* __restrict__ temp, float* __restrict__ A) {
    const int h = blockIdx.x, b = blockIdx.y;
    const int i = threadIdx.x;
    if (i >= 48) return;
    const float* sq = sumsq + b * OC3 + h * D_;
    const float* sk = sumsq + b * OC3 + 192 + h * D_;
    const float t = temp[h];
    const float* Sp = Spart + ((size_t)(b * HEADS_ + h) * 32) * 2304;

    const float rqi = 1.0f / fmaxf(sqrtf(sq[i]), 1e-12f);

    float s[48];
#pragma unroll
    for (int j = 0; j < 48; ++j) {
        float v = 0.f;
        for (int sl = 0; sl < 32; ++sl) v += Sp[sl * 2304 + i * 48 + j];
        s[j] = v * rqi * (1.0f / fmaxf(sqrtf(sk[j]), 1e-12f)) * t;
    }
    float m = -1e30f;
#pragma unroll
    for (int j = 0; j < 48; ++j) m = fmaxf(m, s[j]);
    float sum = 0.f;
#pragma unroll
    for (int j = 0; j < 48; ++j) { s[j] = expf(s[j] - m); sum += s[j]; }
    float inv = 1.0f / sum;
    float* Ao = A + ((size_t)(b * HEADS_ + h) * 48 + i) * 48;
#pragma unroll
    for (int j = 0; j < 48; ++j) Ao[j] = s[j] * inv;
}

// ---------------------------------------------------------------------------
// Wf[b][o][c'] = sum_i proj_w[o][h*48+i] * A[b,h][i][j]   (c' = h*48+j)
// ---------------------------------------------------------------------------
__global__ void wfuse(const float* __restrict__ proj_w, const float* __restrict__ A,
                      __bf16* __restrict__ Wf) {
    const int o = blockIdx.x, b = blockIdx.y;
    const int cp = threadIdx.x;
    const int h = cp / 48, j = cp % 48;
    const float* wrow = proj_w + o * C_ + h * D_;
    const float* Ah = A + (size_t)(b * HEADS_ + h) * 2304;
    float s = 0.f;
#pragma unroll
    for (int i = 0; i < 48; ++i) s += wrow[i] * Ah[i * 48 + j];
    Wf[((size_t)b * 256 + o) * C_ + cp] = (__bf16)s;
}

// ---------------------------------------------------------------------------
extern "C" void kernel_launch(void* const* d_in, const int* in_sizes, int n_in,
                              void* d_out, int out_size, void* d_ws, size_t ws_size,
                              hipStream_t stream) {
    const float* x      = (const float*)d_in[0];
    const float* qkv_w  = (const float*)d_in[1];
    const float* qkv_b  = (const float*)d_in[2];
    const float* dw_w   = (const float*)d_in[3];
    const float* dw_b   = (const float*)d_in[4];
    const float* temp   = (const float*)d_in[5];
    const float* proj_w = (const float*)d_in[6];
    const float* proj_b = (const float*)d_in[7];
    float* out = (float*)d_out;

    char* ws = (char*)d_ws;
    const size_t XT_BYTES  = (size_t)B_ * HW_ * C_ * 2;      // 50,331,648
    const size_t WQ_BYTES  = 640 * C_ * 2;                   // 245,760 (padded)
    const size_t WF_BYTES  = (size_t)B_ * 256 * C_ * 2;      // 786,432 (padded)
    const size_t QKV_BYTES = (size_t)B_ * OC3 * HW_ * 2;     // 150,994,944

    size_t off = 0;
    __bf16* Xt    = (__bf16*)(ws + off); off += XT_BYTES;    // later reused as vt
    __bf16* Wq    = (__bf16*)(ws + off); off += WQ_BYTES;
    __bf16* Wf    = (__bf16*)(ws + off); off += WF_BYTES;
    bf16*   bufA  = (bf16*)(ws + off);   off += QKV_BYTES;   // qkv after 1x1
    bf16*   bufB  = (bf16*)(ws + off);   off += QKV_BYTES;   // qkv after dwconv
    float*  sumsq = (float*)(ws + off);  off += OC3 * B_ * 4;
    float*  Spart = (float*)(ws + off);  off += (size_t)32 * 2304 * 4 * 32; // 9.4 MB
    float*  Attn  = (float*)(ws + off);  off += 294912;
    __bf16* vt    = Xt;  // Xt dead after qkv GEMM

    cvt_w<<<dim3(OC3), 192, 0, stream>>>(qkv_w, Wq);

    tx_cvt<<<dim3(HW_ / 128, 1, B_), 256, 0, stream>>>(x, Xt);

    mfma_gemm<bf16><<<dim3(HW_ / 128, 5, B_), 256, 0, stream>>>(
        Wq, Xt, qkv_b, bufA, OC3, C_, 0);

    dwconv_fused<<<dim3(OC3, B_), 256, 0, stream>>>(bufA, dw_w, dw_b, bufB, sumsq);

    qk_mfma<<<dim3(32, HEADS_, B_), 256, 0, stream>>>(bufB, Spart);

    softmax48<<<dim3(HEADS_, B_), 64, 0, stream>>>(Spart, sumsq, temp, Attn);

    vtx<<<dim3(HW_ / 128, 1, B_), 256, 0, stream>>>(bufB, vt);

    wfuse<<<dim3(C_, B_), 192, 0, stream>>>(proj_w, Attn, Wf);

    mfma_gemm<float><<<dim3(HW_ / 128, 2, B_), 256, 0, stream>>>(
        Wf, vt, proj_b, out, C_, C_, (size_t)256 * C_);
}